// Round 1
// 3179.807 us; speedup vs baseline: 1.5912x; 1.5912x over previous
//
#include <hip/hip_runtime.h>
#include <hip/hip_bf16.h>
#include <cstdint>
#include <cstddef>

#define VOCABN 10000
#define FEATC 512
#define EMBN 256
#define HIDN 512
#define AFFN 512
#define BB 32
#define TTN 60
#define PPN 196
#define XKN 1280   // x layout per batch: emb[0,256) | ctx[256,768) | h[768,1280)

using bf16 = __hip_bfloat16;

typedef __attribute__((ext_vector_type(8))) short short8;
typedef __attribute__((ext_vector_type(4))) float f32x4;

__device__ __forceinline__ float b2f(bf16 x){ return __bfloat162float(x); }
__device__ __forceinline__ float fexp2(float x){ return __builtin_amdgcn_exp2f(x); }
__device__ __forceinline__ float frcp(float x){ return __builtin_amdgcn_rcpf(x); }
__device__ __forceinline__ float fsig(float x){ return frcp(1.f + fexp2(-1.4426950408889634f*x)); }
__device__ __forceinline__ float ftanhf(float x){ return 1.f - 2.f*frcp(1.f + fexp2(2.8853900817779268f*x)); }

__device__ __forceinline__ void unpack8(uint4 u, float* f){
  f[0] = __uint_as_float(u.x << 16); f[1] = __uint_as_float(u.x & 0xffff0000u);
  f[2] = __uint_as_float(u.y << 16); f[3] = __uint_as_float(u.y & 0xffff0000u);
  f[4] = __uint_as_float(u.z << 16); f[5] = __uint_as_float(u.z & 0xffff0000u);
  f[6] = __uint_as_float(u.w << 16); f[7] = __uint_as_float(u.w & 0xffff0000u);
}

// ---------- dtype probe ----------
__global__ void __launch_bounds__(256) k_probe(const uint32_t* __restrict__ w, int* __restrict__ flag){
  __shared__ int s;
  if (threadIdx.x == 0) s = 0;
  __syncthreads();
  int hit = 0;
  for (int i = threadIdx.x; i < 32768; i += 256){
    uint32_t v = w[i];
    if (((v & 0x7F800000u) == 0x7F800000u) || ((v & 0x00007F80u) == 0x00007F80u)) hit = 1;
  }
  if (hit) atomicOr(&s, 1);
  __syncthreads();
  if (threadIdx.x == 0) flag[0] = s;
}

// ---------- canonicalize one tensor to bf16 ----------
__global__ void __launch_bounds__(256) k_cvt(const void* __restrict__ src, bf16* __restrict__ dst,
                                             int nquad, const int* __restrict__ flag){
  bool f32 = flag[0] != 0;
  int stride = gridDim.x * 256;
  for (int i = blockIdx.x*256 + threadIdx.x; i < nquad; i += stride){
    if (f32){
      float4 v = reinterpret_cast<const float4*>(src)[i];
      bf16* d = dst + 4*(size_t)i;
      d[0] = __float2bfloat16(v.x); d[1] = __float2bfloat16(v.y);
      d[2] = __float2bfloat16(v.z); d[3] = __float2bfloat16(v.w);
    } else {
      reinterpret_cast<uint2*>(dst)[i] = reinterpret_cast<const uint2*>(src)[i];
    }
  }
}

// ---------- feats[b][p][c] = cnn[b][c][p] ----------
__global__ void __launch_bounds__(256) k_transpose(const bf16* __restrict__ cnn, bf16* __restrict__ feats){
  __shared__ bf16 tile[32][34];
  int ct = blockIdx.x, pt = blockIdx.y, b = blockIdx.z;
  int tid = threadIdx.x;
  int lc = tid >> 5, lp = tid & 31;
  int p = pt*32 + lp;
  #pragma unroll
  for (int i=0;i<4;i++){
    int cc = ct*32 + lc + i*8;
    bf16 v = __float2bfloat16(0.f);
    if (p < PPN) v = cnn[((size_t)b*FEATC + cc)*PPN + p];
    tile[lc + i*8][lp] = v;
  }
  __syncthreads();
  #pragma unroll
  for (int i=0;i<4;i++){
    int pp = pt*32 + lc + i*8;
    if (pp < PPN) feats[((size_t)b*PPN + pp)*FEATC + ct*32 + lp] = tile[lp][lc + i*8];
  }
}

// ---------- WkT = Wk^T (512x512 bf16) ----------
__global__ void __launch_bounds__(256) k_wkt(const bf16* __restrict__ W, bf16* __restrict__ WT){
  __shared__ bf16 tile[32][33];
  const int c0 = blockIdx.x*32, r0 = blockIdx.y*32;
  const int lc = threadIdx.x >> 5, lp = threadIdx.x & 31;
  #pragma unroll
  for (int i=0;i<4;i++) tile[lc + i*8][lp] = W[(size_t)(r0 + lc + i*8)*HIDN + c0 + lp];
  __syncthreads();
  #pragma unroll
  for (int i=0;i<4;i++) WT[(size_t)(c0 + lc + i*8)*HIDN + r0 + lp] = tile[lp][lc + i*8];
}

// ---------- Wcat[r'][0..1280) : r' = j*4+gate, row = [Wih(g*512+j) | Whh(g*512+j)] ----------
__global__ void __launch_bounds__(256) k_wcat(const bf16* __restrict__ Wih, const bf16* __restrict__ Whh,
      const bf16* __restrict__ bih, const bf16* __restrict__ bhh,
      bf16* __restrict__ Wcat, float* __restrict__ biasCat){
  const int rloc = threadIdx.x >> 5, lane32 = threadIdx.x & 31;
  const int r = blockIdx.x*8 + rloc;
  const int j = r >> 2, g = r & 3;
  const int src = g*HIDN + j;
  for (int e4 = lane32; e4 < 320; e4 += 32){
    const int e = e4*4;
    uint2 v = (e < 768) ? *reinterpret_cast<const uint2*>(Wih + (size_t)src*768 + e)
                        : *reinterpret_cast<const uint2*>(Whh + (size_t)src*HIDN + (e - 768));
    *reinterpret_cast<uint2*>(Wcat + (size_t)r*XKN + e) = v;
  }
  if (lane32 == 0) biasCat[r] = b2f(bih[src]) + b2f(bhh[src]);
}

// ---------- g = mean_p cnn ; h0 = g@Wh^T+bh ; c0 = g@Wc^T+bc ----------
__global__ void __launch_bounds__(256) k_init(const bf16* __restrict__ cnn,
      const bf16* __restrict__ Wh, const bf16* __restrict__ bh,
      const bf16* __restrict__ Wc, const bf16* __restrict__ bc,
      float* __restrict__ h, float* __restrict__ c){
  __shared__ float gl[FEATC];
  int b = blockIdx.x, tid = threadIdx.x;
  for (int cc = tid; cc < FEATC; cc += 256){
    const bf16* src = cnn + ((size_t)b*FEATC + cc)*PPN;
    const uint2* sp = reinterpret_cast<const uint2*>(src);
    float acc = 0.f;
    for (int q=0;q<PPN/4;q++){
      uint2 u = sp[q];
      acc += __uint_as_float(u.x<<16) + __uint_as_float(u.x&0xffff0000u)
           + __uint_as_float(u.y<<16) + __uint_as_float(u.y&0xffff0000u);
    }
    gl[cc] = acc * (1.0f/196.0f);
  }
  __syncthreads();
  for (int i = tid; i < HIDN; i += 256){
    const uint4* wr1 = reinterpret_cast<const uint4*>(Wh + (size_t)i*FEATC);
    const uint4* wr2 = reinterpret_cast<const uint4*>(Wc + (size_t)i*FEATC);
    float a1 = 0.f, a2 = 0.f;
    #pragma unroll 4
    for (int k8=0; k8<FEATC/8; k8++){
      float w1[8], w2[8];
      unpack8(wr1[k8], w1); unpack8(wr2[k8], w2);
      const float* gp = &gl[k8*8];
      #pragma unroll
      for (int j=0;j<8;j++){ a1 = fmaf(w1[j], gp[j], a1); a2 = fmaf(w2[j], gp[j], a2); }
    }
    h[b*HIDN+i] = a1 + b2f(bh[i]);
    c[b*HIDN+i] = a2 + b2f(bc[i]);
  }
}

// ---------- initial hk partials from h0 (parity 0) ----------
__global__ void __launch_bounds__(512) k_hk0(const bf16* __restrict__ WkT,
      const float* __restrict__ h, float* __restrict__ part){
  __shared__ float hl[64];
  const int tid = threadIdx.x;
  const int k = blockIdx.x & 7, b = blockIdx.x >> 3;
  if (tid < 64) hl[tid] = h[b*HIDN + k*64 + tid];
  __syncthreads();
  const bf16* wp = WkT + (size_t)(k*64)*AFFN + tid;
  float acc = 0.f;
  #pragma unroll 8
  for (int j=0; j<64; j++) acc = fmaf(b2f(wp[(size_t)j*AFFN]), hl[j], acc);
  part[((size_t)(b*8 + k))*AFFN + tid] = acc;
}

// ---------- generic MFMA GEMM: C[M][N] = A[M][K] @ Bw[N][K]^T (+bias) ----------
// OUTMODE 0: f32 out. 1: dtype by flag (1->f32, 0->bf16). 2: always bf16.
template<int OUTMODE, bool BIAS>
__global__ void __launch_bounds__(256) gemm_bt(const bf16* __restrict__ A, const bf16* __restrict__ Bw,
        const bf16* __restrict__ bias, void* __restrict__ Cout, int M, int N, int K,
        const int* __restrict__ flag){
  __shared__ __align__(16) bf16 As[64][40];
  __shared__ __align__(16) bf16 Bs[64][40];
  int tid = threadIdx.x;
  int m0 = blockIdx.y*64, n0 = blockIdx.x*64;
  int lr = tid >> 2;
  int lk = (tid & 3)*8;
  int wave = tid >> 6, lane = tid & 63;
  int ml = lane & 15, kg = lane >> 4;
  f32x4 acc0 = {0.f,0.f,0.f,0.f}, acc1 = acc0, acc2 = acc0, acc3 = acc0;
  for (int k0=0; k0<K; k0+=32){
    __syncthreads();
    {
      uint4 av = *reinterpret_cast<const uint4*>(A + (size_t)(m0+lr)*K + k0 + lk);
      *reinterpret_cast<uint4*>(&As[lr][lk]) = av;
      uint4 bv = make_uint4(0u,0u,0u,0u);
      int bn = n0 + lr;
      if (bn < N) bv = *reinterpret_cast<const uint4*>(Bw + (size_t)bn*K + k0 + lk);
      *reinterpret_cast<uint4*>(&Bs[lr][lk]) = bv;
    }
    __syncthreads();
    short8 af = *reinterpret_cast<const short8*>(&As[wave*16 + ml][kg*8]);
    short8 b0 = *reinterpret_cast<const short8*>(&Bs[ 0 + ml][kg*8]);
    short8 b1 = *reinterpret_cast<const short8*>(&Bs[16 + ml][kg*8]);
    short8 b2 = *reinterpret_cast<const short8*>(&Bs[32 + ml][kg*8]);
    short8 b3 = *reinterpret_cast<const short8*>(&Bs[48 + ml][kg*8]);
    acc0 = __builtin_amdgcn_mfma_f32_16x16x32_bf16(af, b0, acc0, 0,0,0);
    acc1 = __builtin_amdgcn_mfma_f32_16x16x32_bf16(af, b1, acc1, 0,0,0);
    acc2 = __builtin_amdgcn_mfma_f32_16x16x32_bf16(af, b2, acc2, 0,0,0);
    acc3 = __builtin_amdgcn_mfma_f32_16x16x32_bf16(af, b3, acc3, 0,0,0);
  }
  bool of32;
  if (OUTMODE == 0) of32 = true;
  else if (OUTMODE == 2) of32 = false;
  else of32 = (flag[0] != 0);
  int mb = m0 + wave*16 + (lane>>4)*4;
  int cl = lane & 15;
  f32x4 av[4] = {acc0, acc1, acc2, acc3};
  #pragma unroll
  for (int j=0;j<4;j++){
    int n = n0 + j*16 + cl;
    if (n < N){
      float bv = BIAS ? b2f(bias[n]) : 0.f;
      #pragma unroll
      for (int rr=0; rr<4; rr++){
        float v = av[j][rr] + bv;
        if (of32) ((float*)Cout)[(size_t)(mb+rr)*N + n] = v;
        else      ((bf16*)Cout)[(size_t)(mb+rr)*N + n] = __float2bfloat16(v);
      }
    }
  }
}

// ---------- the fused per-step kernel ----------
// grid: 256 blocks, b = blockIdx>>3, slice k = blockIdx&7 (same k -> same XCD for weight-slice L2 residency)
// block: 512 threads. Phases: hk-sum | z | softmax | ctx | gates-slice | cell | next hk-partial.
__global__ void __launch_bounds__(512) k_step(
    const bf16* __restrict__ kvB, const bf16* __restrict__ feats,
    const bf16* __restrict__ WkT, const bf16* __restrict__ Wcat,
    const float* __restrict__ biasCat, const bf16* __restrict__ wa,
    const bf16* __restrict__ table, const int* __restrict__ captions,
    const float* __restrict__ hR, float* __restrict__ hW,
    float* __restrict__ c,
    const float* __restrict__ partR, float* __restrict__ partW,
    bf16* __restrict__ Hb, int t)
{
  __shared__ __align__(16) float xs[XKN];    // emb | ctx | h
  __shared__ __align__(16) float hks[AFFN];
  __shared__ __align__(16) float als[PPN];
  __shared__ __align__(16) float gs[256];
  __shared__ float hnew[64];

  const int tid = threadIdx.x;
  const int k = blockIdx.x & 7, b = blockIdx.x >> 3;
  const int lane = tid & 63, wv = tid >> 6;

  // P0: emb, h, hk = sum of 8 partials
  const int tok = captions[b*TTN + t];
  if (tid < EMBN) xs[tid] = b2f(table[(size_t)tok*EMBN + tid]);
  xs[EMBN + FEATC + tid] = hR[b*HIDN + tid];
  {
    const float* pp = partR + (size_t)b*8*AFFN + tid;
    float s = pp[0];
    #pragma unroll
    for (int kk=1; kk<8; kk++) s += pp[(size_t)kk*AFFN];
    hks[tid] = s;
  }
  __syncthreads();

  // P1: z[p] = sum_a wa[a]*tanh(hk[a]+kv[b][p][a]); wave per p
  float wf[8], hf[8];
  unpack8(*reinterpret_cast<const uint4*>(wa + lane*8), wf);
  {
    const float4* hp = reinterpret_cast<const float4*>(&hks[lane*8]);
    float4 t0 = hp[0], t1 = hp[1];
    hf[0]=t0.x; hf[1]=t0.y; hf[2]=t0.z; hf[3]=t0.w;
    hf[4]=t1.x; hf[5]=t1.y; hf[6]=t1.z; hf[7]=t1.w;
  }
  for (int p = wv; p < PPN; p += 16){
    const int p2 = (p + 8 < PPN) ? p + 8 : p;
    float kf0[8], kf1[8];
    unpack8(*reinterpret_cast<const uint4*>(kvB + ((size_t)(b*PPN + p ))*AFFN + lane*8), kf0);
    unpack8(*reinterpret_cast<const uint4*>(kvB + ((size_t)(b*PPN + p2))*AFFN + lane*8), kf1);
    float acc = wf[0]*ftanhf(kf0[0]+hf[0]) + wf[1]*ftanhf(kf0[1]+hf[1])
              + wf[2]*ftanhf(kf0[2]+hf[2]) + wf[3]*ftanhf(kf0[3]+hf[3])
              + wf[4]*ftanhf(kf0[4]+hf[4]) + wf[5]*ftanhf(kf0[5]+hf[5])
              + wf[6]*ftanhf(kf0[6]+hf[6]) + wf[7]*ftanhf(kf0[7]+hf[7]);
    #pragma unroll
    for (int s=1;s<64;s<<=1) acc += __shfl_xor(acc, s, 64);
    if (lane == 0) als[p] = acc;
    if (p2 != p){
      float a2 = wf[0]*ftanhf(kf1[0]+hf[0]) + wf[1]*ftanhf(kf1[1]+hf[1])
               + wf[2]*ftanhf(kf1[2]+hf[2]) + wf[3]*ftanhf(kf1[3]+hf[3])
               + wf[4]*ftanhf(kf1[4]+hf[4]) + wf[5]*ftanhf(kf1[5]+hf[5])
               + wf[6]*ftanhf(kf1[6]+hf[6]) + wf[7]*ftanhf(kf1[7]+hf[7]);
      #pragma unroll
      for (int s=1;s<64;s<<=1) a2 += __shfl_xor(a2, s, 64);
      if (lane == 0) als[p2] = a2;
    }
  }
  __syncthreads();

  // P2: softmax over 196 (wave 0)
  if (wv == 0){
    float m = -1e30f;
    for (int i=lane; i<PPN; i+=64) m = fmaxf(m, als[i]);
    #pragma unroll
    for (int s=1;s<64;s<<=1) m = fmaxf(m, __shfl_xor(m, s, 64));
    float ssum = 0.f;
    for (int i=lane; i<PPN; i+=64){
      float e = fexp2((als[i]-m)*1.4426950408889634f);
      als[i] = e; ssum += e;
    }
    #pragma unroll
    for (int s=1;s<64;s<<=1) ssum += __shfl_xor(ssum, s, 64);
    float inv = 1.0f / ssum;
    for (int i=lane; i<PPN; i+=64) als[i] *= inv;
  }
  __syncthreads();

  // P3: ctx[c] = sum_p alpha[p]*feats[b][p][c]; thread = c, coalesced
  {
    const bf16* fb = feats + (size_t)b*PPN*FEATC + tid;
    float c0=0.f,c1=0.f,c2=0.f,c3=0.f;
    for (int p=0; p<PPN; p+=4){
      c0 = fmaf(b2f(fb[(size_t)(p+0)*FEATC]), als[p+0], c0);
      c1 = fmaf(b2f(fb[(size_t)(p+1)*FEATC]), als[p+1], c1);
      c2 = fmaf(b2f(fb[(size_t)(p+2)*FEATC]), als[p+2], c2);
      c3 = fmaf(b2f(fb[(size_t)(p+3)*FEATC]), als[p+3], c3);
    }
    xs[EMBN + tid] = (c0+c1)+(c2+c3);
  }
  __syncthreads();

  // P4: gate slice, 2 threads per row (k-halves), row' = j*4+gate interleave
  {
    const int r = tid >> 1, half = tid & 1;
    const int rowg = k*256 + r;
    const bf16* wrow = Wcat + (size_t)rowg*XKN + half*640;
    const float* xp = xs + half*640;
    float a0=0.f,a1=0.f,a2=0.f,a3=0.f;
    #pragma unroll 4
    for (int e=0; e<640; e+=8){
      float w8[8]; unpack8(*reinterpret_cast<const uint4*>(wrow + e), w8);
      float4 x0 = *reinterpret_cast<const float4*>(xp + e);
      float4 x1 = *reinterpret_cast<const float4*>(xp + e + 4);
      a0 = fmaf(w8[0],x0.x,a0); a1 = fmaf(w8[1],x0.y,a1);
      a2 = fmaf(w8[2],x0.z,a2); a3 = fmaf(w8[3],x0.w,a3);
      a0 = fmaf(w8[4],x1.x,a0); a1 = fmaf(w8[5],x1.y,a1);
      a2 = fmaf(w8[6],x1.z,a2); a3 = fmaf(w8[7],x1.w,a3);
    }
    float acc = (a0+a1)+(a2+a3);
    acc += __shfl_xor(acc, 1, 64);
    if (half == 0) gs[r] = acc + biasCat[rowg];
  }
  __syncthreads();

  // P5: LSTM cell for this block's 64 j's
  if (tid < 64){
    const int j = k*64 + tid;
    float gi = gs[tid*4+0], gf = gs[tid*4+1], gg = gs[tid*4+2], go = gs[tid*4+3];
    float cold = c[b*HIDN + j];
    float cn = fsig(gf)*cold + fsig(gi)*ftanhf(gg);
    float hn = fsig(go)*ftanhf(cn);
    c[b*HIDN + j] = cn;
    hW[b*HIDN + j] = hn;
    Hb[((size_t)b*TTN + t)*HIDN + j] = __float2bfloat16(hn);
    hnew[tid] = hn;
  }
  __syncthreads();

  // P6: next step's hk partial over our h slice (no Wk redundancy)
  {
    const bf16* wp = WkT + (size_t)(k*64)*AFFN + tid;
    float acc = 0.f;
    #pragma unroll 8
    for (int j=0; j<64; j++)
      acc = fmaf(b2f(wp[(size_t)j*AFFN]), hnew[j], acc);
    partW[((size_t)(b*8 + k))*AFFN + tid] = acc;
  }
}

static inline int cvt_grid(int nquad){ int g = (nquad + 255)/256; return g > 1024 ? 1024 : g; }

extern "C" void kernel_launch(void* const* d_in, const int* in_sizes, int n_in,
                              void* d_out, int out_size, void* d_ws, size_t ws_size,
                              hipStream_t stream) {
  const int* captions = (const int*)d_in[1];
  char* ws = (char*)d_ws;

  // ---- workspace layout (bytes) ----
  bf16*  feats  = (bf16*) (ws + 0);          // [6272][512] bf16
  bf16*  kvB    = (bf16*) (ws + 6422528);    // [6272][512] bf16
  float* h      = (float*)(ws + 12845056);   // [2][32][512] f32 (parity dbuf)
  float* c      = (float*)(ws + 12976128);   // [32][512] f32
  float* part   = (float*)(ws + 13041664);   // [2][32][8][512] f32 (parity dbuf)
  bf16*  Hb     = (bf16*) (ws + 14090240);   // [32][60][512] bf16
  bf16*  cnnB   = (bf16*) (ws + 16056320);   // [32][512][196] bf16 (dead after transpose+init)
  bf16*  WcatB  = (bf16*) (ws + 16056320);   // [2048][1280] bf16 — ALIASES cnnB, built after cnnB is dead
  bf16*  tableB = (bf16*) (ws + 22478848);
  bf16*  WkB    = (bf16*) (ws + 27598848);
  bf16*  WkTB   = (bf16*) (ws + 28123136);
  bf16*  WvB    = (bf16*) (ws + 28647424);
  bf16*  WhB    = (bf16*) (ws + 29171712);
  bf16*  WcB    = (bf16*) (ws + 29696000);
  bf16*  WihB   = (bf16*) (ws + 30220288);
  bf16*  WhhB   = (bf16*) (ws + 33366016);
  bf16*  WfcB   = (bf16*) (ws + 35463168);
  bf16*  waB    = (bf16*) (ws + 45703168);
  bf16*  bhB    = (bf16*) (ws + 45704192);
  bf16*  bcB    = (bf16*) (ws + 45705216);
  bf16*  bihB   = (bf16*) (ws + 45706240);
  bf16*  bhhB   = (bf16*) (ws + 45710336);
  bf16*  bfcB   = (bf16*) (ws + 45714432);
  float* biasCat= (float*)(ws + 45734432);
  int*   flag   = (int*)  (ws + 45742624);
  if (ws_size < 45742640ull) return;

  // 1) dtype probe
  k_probe<<<1, 256, 0, stream>>>((const uint32_t*)d_in[5], flag);

  // 2) canonicalize to bf16
  struct CvtJob { const void* src; bf16* dst; int n; };
  const CvtJob jobs[15] = {
    {d_in[0],  cnnB,   3211264}, {d_in[2],  WkB,  262144}, {d_in[3],  WvB,  262144},
    {d_in[4],  waB,    512},     {d_in[5],  tableB, 2560000},
    {d_in[6],  WhB,    262144},  {d_in[7],  bhB,  512},
    {d_in[8],  WcB,    262144},  {d_in[9],  bcB,  512},
    {d_in[10], WihB,   1572864}, {d_in[11], WhhB, 1048576},
    {d_in[12], bihB,   2048},    {d_in[13], bhhB, 2048},
    {d_in[14], WfcB,   5120000}, {d_in[15], bfcB, 10000},
  };
  for (int i = 0; i < 15; i++){
    int nq = jobs[i].n / 4;
    k_cvt<<<cvt_grid(nq), 256, 0, stream>>>(jobs[i].src, jobs[i].dst, nq, flag);
  }

  // 3) precompute (order matters: cnnB consumers BEFORE k_wcat overwrites that region)
  k_transpose<<<dim3(16,7,32), 256, 0, stream>>>(cnnB, feats);
  k_init<<<32, 256, 0, stream>>>(cnnB, WhB, bhB, WcB, bcB, h, c);   // h parity 0
  k_wkt<<<dim3(16,16), 256, 0, stream>>>(WkB, WkTB);
  k_wcat<<<256, 256, 0, stream>>>(WihB, WhhB, bihB, bhhB, WcatB, biasCat);
  k_hk0<<<256, 512, 0, stream>>>(WkTB, h, part);                    // part parity 0
  gemm_bt<2,false><<<dim3(8,98), 256, 0, stream>>>(feats, WvB, (const bf16*)nullptr,
                                                   (void*)kvB, 6272, 512, 512, (const int*)nullptr);

  // 4) recurrence: ONE fused kernel per step, parity double-buffered h / hk-partials
  const size_t HP = (size_t)BB*HIDN;     // 16384 floats
  const size_t PQ = (size_t)BB*8*AFFN;   // 131072 floats
  for (int t = 0; t < TTN; t++){
    const float* hR = h + (size_t)(t&1)*HP;
    float*       hWp= h + (size_t)((t+1)&1)*HP;
    const float* pR = part + (size_t)(t&1)*PQ;
    float*       pW = part + (size_t)((t+1)&1)*PQ;
    k_step<<<256, 512, 0, stream>>>(kvB, feats, WkTB, WcatB, biasCat, waB, tableB,
                                    captions, hR, hWp, c, pR, pW, Hb, t);
  }

  // 5) logits = Hb @ Wfc^T + bfc
  gemm_bt<1,true><<<dim3(157,30), 256, 0, stream>>>(Hb, WfcB, bfcB, d_out,
                                                    1920, 10000, 512, flag);
}